// Round 14
// baseline (262.298 us; speedup 1.0000x reference)
//
#include <hip/hip_runtime.h>

// Lee oscillator — R13 base + uniform x3-stream kernel B (zero-tail schedule).
//  All trajectories cost identical time -> assign EVERY thread identical work
//  in ONE wave-generation: T = 2048*256 threads (exactly fills 8192 wave
//  slots), each runs 3 independent streams on entries (j, j+T, j+2T),
//  dummy-padded past m. No ceil-quantization tail (R11-R13 all lost ~25%
//  to it), ILP=3 hides VALU latency.
// The type-1-ALGEBRAICALLY-SPECIALIZED body remains excluded (6/6 fail
// correlation); all trajectory code is the generic bitwise-verified sequence,
// verbatim per stream. Skip rule: t==1 & gate<4e-3 -> |L_ref-omega| <= 8e-3
// < 0.02 (a1=b1=0 => L never feeds back); measured 1 bf16 ulp.

#pragma clang fp contract(off)

#define N_ITERS 99                            // N_STEPS - 1
#define LOG_GATE_THRESH -5.5214609178622464f  // ln(4e-3)
#define BLOCK 256
#define ITERS_PER_WAVE 64
#define WSPAN (64 * ITERS_PER_WAVE)           // 4096 elements per wave
#define SPAN (4 * WSPAN)                      // 16384 elements per block
#define WL_CAP 512                            // per-wave LDS cap (mean ~340, +9 sigma)
#define B_BLOCKS 2048                         // kernel B grid: exactly one residency

// (a1,a2,a3,a4, b1,b2,b3,b4, xi_E, xi_I) for oscillator types 1..8
__device__ __constant__ float kCoeffs[8][10] = {
    { 0.0f,  5.0f,   5.0f,   1.0f,  0.0f, -1.0f,   1.0f,  0.0f, 0.0f, 0.0f},
    { 0.5f,  0.55f,  0.55f, -0.5f,  0.5f, -0.55f, -0.55f, -0.5f, 0.0f, 0.0f},
    {-5.0f,  5.0f,   5.0f,  -5.0f,  1.0f, -1.0f,  -1.0f,  1.0f, 0.0f, 0.0f},
    { 1.0f,  1.0f,   1.0f,  -1.0f, -1.0f, -1.0f,  -1.0f,  1.0f, 0.0f, 0.0f},
    { 5.0f, -5.0f,  -5.0f,   5.0f, -1.0f,  1.0f,   1.0f, -1.0f, 0.0f, 0.0f},
    {-1.0f, -1.0f,  -1.0f,   1.0f,  1.0f,  1.0f,   1.0f, -1.0f, 0.0f, 0.0f},
    { 1.0f, -1.0f,  -1.0f,   1.0f, -1.0f,  1.0f,   1.0f, -1.0f, 0.0f, 0.0f},
    {-1.0f,  1.0f,   1.0f,  -1.0f,  1.0f, -1.0f,  -1.0f,  1.0f, 0.0f, 0.0f},
};

// XLA EmitFastTanh / Eigen generic_fast_tanh_float, with_fma variant.
// Every op correctly rounded -> bitwise reproducible. (R1/R7/R8/R10-R13.)
__device__ __forceinline__ float xla_fast_tanh(float x) {
#pragma clang fp contract(off)
    const float kClamp = 7.99881172180175781f;
    float ax = __builtin_fabsf(x);
    float xc = __builtin_fminf(__builtin_fmaxf(x, -kClamp), kClamp);
    float x2 = __fmul_rn(xc, xc);
    float p = __fmaf_rn(x2, -2.76076847742355e-16f, 2.00018790482477e-13f);
    p = __fmaf_rn(x2, p, -8.60467152213735e-11f);
    p = __fmaf_rn(x2, p, 5.12229709037114e-08f);
    p = __fmaf_rn(x2, p, 1.48572235717979e-05f);
    p = __fmaf_rn(x2, p, 6.37261928875436e-04f);
    p = __fmaf_rn(x2, p, 4.89352455891786e-03f);
    p = __fmul_rn(xc, p);
    float q = __fmaf_rn(x2, 1.19825839466702e-06f, 1.18534705686654e-04f);
    q = __fmaf_rn(x2, q, 2.26843463243900e-03f);
    q = __fmaf_rn(x2, q, 4.89352518554385e-03f);
    float r = p / q;  // IEEE-correct f32 division
    return (ax < 0.0004f) ? x : r;
}

// Generic exact trajectory (ALL types) — verbatim R1/R7 (verified bitwise).
__device__ __forceinline__ float lee_compute(float xv, const float* c) {
#pragma clang fp contract(off)
    const float a1 = c[0], a2 = c[1], a3 = c[2], a4 = c[3];
    const float b1 = c[4], b2 = c[5], b3 = c[6], b4 = c[7];
    const float xiE = c[8], xiI = c[9];

    float sgn = (xv > 0.0f) ? 1.0f : ((xv < 0.0f) ? -1.0f : 0.0f);
    float sim = __fadd_rn(xv, __fmul_rn(0.001f, sgn));
    float gq = __fmul_rn(__fmul_rn(-500.0f, sim), sim);
    float gate = expf(gq);
    float omega = xla_fast_tanh(__fmul_rn(5.0f, sim));

    float E = 0.2f, I = 0.0f, L = 0.2f;
    for (int s = 0; s < N_ITERS; ++s) {
        float tE = __fmul_rn(a1, L);
        tE = __fadd_rn(tE, __fmul_rn(a2, E));
        tE = __fsub_rn(tE, __fmul_rn(a3, I));
        tE = __fadd_rn(tE, __fmul_rn(a4, sim));
        tE = __fsub_rn(tE, xiE);
        float E1 = xla_fast_tanh(__fmul_rn(5.0f, tE));

        float tI = __fmul_rn(b1, L);
        tI = __fsub_rn(tI, __fmul_rn(b2, E));
        tI = __fsub_rn(tI, __fmul_rn(b3, I));
        tI = __fadd_rn(tI, __fmul_rn(b4, sim));
        tI = __fsub_rn(tI, xiI);
        float I1 = xla_fast_tanh(__fmul_rn(5.0f, tI));

        L = __fadd_rn(__fmul_rn(__fsub_rn(E1, I1), gate), omega);
        E = E1;
        I = I1;
    }
    return L;
}

// Three independent streams in one loop — each stream's op sequence is a
// VERBATIM copy of lee_compute's (no algebraic specialization). Triples
// in-lane ILP; used with a uniform zero-tail schedule in kernel B.
__device__ __forceinline__ void lee_compute_x3(float xv0, float xv1, float xv2,
                                               const float* c,
                                               float* L0o, float* L1o, float* L2o) {
#pragma clang fp contract(off)
    const float a1 = c[0], a2 = c[1], a3 = c[2], a4 = c[3];
    const float b1 = c[4], b2 = c[5], b3 = c[6], b4 = c[7];
    const float xiE = c[8], xiI = c[9];

    float sgn0 = (xv0 > 0.0f) ? 1.0f : ((xv0 < 0.0f) ? -1.0f : 0.0f);
    float sgn1 = (xv1 > 0.0f) ? 1.0f : ((xv1 < 0.0f) ? -1.0f : 0.0f);
    float sgn2 = (xv2 > 0.0f) ? 1.0f : ((xv2 < 0.0f) ? -1.0f : 0.0f);
    float sim0 = __fadd_rn(xv0, __fmul_rn(0.001f, sgn0));
    float sim1 = __fadd_rn(xv1, __fmul_rn(0.001f, sgn1));
    float sim2 = __fadd_rn(xv2, __fmul_rn(0.001f, sgn2));
    float gq0 = __fmul_rn(__fmul_rn(-500.0f, sim0), sim0);
    float gq1 = __fmul_rn(__fmul_rn(-500.0f, sim1), sim1);
    float gq2 = __fmul_rn(__fmul_rn(-500.0f, sim2), sim2);
    float gate0 = expf(gq0);
    float gate1 = expf(gq1);
    float gate2 = expf(gq2);
    float omega0 = xla_fast_tanh(__fmul_rn(5.0f, sim0));
    float omega1 = xla_fast_tanh(__fmul_rn(5.0f, sim1));
    float omega2 = xla_fast_tanh(__fmul_rn(5.0f, sim2));

    float E0 = 0.2f, I0 = 0.0f, L0 = 0.2f;
    float E1_ = 0.2f, I1_ = 0.0f, L1 = 0.2f;
    float E2_ = 0.2f, I2_ = 0.0f, L2 = 0.2f;
    for (int s = 0; s < N_ITERS; ++s) {
        float tE0 = __fmul_rn(a1, L0);
        float tE1 = __fmul_rn(a1, L1);
        float tE2 = __fmul_rn(a1, L2);
        tE0 = __fadd_rn(tE0, __fmul_rn(a2, E0));
        tE1 = __fadd_rn(tE1, __fmul_rn(a2, E1_));
        tE2 = __fadd_rn(tE2, __fmul_rn(a2, E2_));
        tE0 = __fsub_rn(tE0, __fmul_rn(a3, I0));
        tE1 = __fsub_rn(tE1, __fmul_rn(a3, I1_));
        tE2 = __fsub_rn(tE2, __fmul_rn(a3, I2_));
        tE0 = __fadd_rn(tE0, __fmul_rn(a4, sim0));
        tE1 = __fadd_rn(tE1, __fmul_rn(a4, sim1));
        tE2 = __fadd_rn(tE2, __fmul_rn(a4, sim2));
        tE0 = __fsub_rn(tE0, xiE);
        tE1 = __fsub_rn(tE1, xiE);
        tE2 = __fsub_rn(tE2, xiE);
        float En0 = xla_fast_tanh(__fmul_rn(5.0f, tE0));
        float En1 = xla_fast_tanh(__fmul_rn(5.0f, tE1));
        float En2 = xla_fast_tanh(__fmul_rn(5.0f, tE2));

        float tI0 = __fmul_rn(b1, L0);
        float tI1 = __fmul_rn(b1, L1);
        float tI2 = __fmul_rn(b1, L2);
        tI0 = __fsub_rn(tI0, __fmul_rn(b2, E0));
        tI1 = __fsub_rn(tI1, __fmul_rn(b2, E1_));
        tI2 = __fsub_rn(tI2, __fmul_rn(b2, E2_));
        tI0 = __fsub_rn(tI0, __fmul_rn(b3, I0));
        tI1 = __fsub_rn(tI1, __fmul_rn(b3, I1_));
        tI2 = __fsub_rn(tI2, __fmul_rn(b3, I2_));
        tI0 = __fadd_rn(tI0, __fmul_rn(b4, sim0));
        tI1 = __fadd_rn(tI1, __fmul_rn(b4, sim1));
        tI2 = __fadd_rn(tI2, __fmul_rn(b4, sim2));
        tI0 = __fsub_rn(tI0, xiI);
        tI1 = __fsub_rn(tI1, xiI);
        tI2 = __fsub_rn(tI2, xiI);
        float In0 = xla_fast_tanh(__fmul_rn(5.0f, tI0));
        float In1 = xla_fast_tanh(__fmul_rn(5.0f, tI1));
        float In2 = xla_fast_tanh(__fmul_rn(5.0f, tI2));

        L0 = __fadd_rn(__fmul_rn(__fsub_rn(En0, In0), gate0), omega0);
        L1 = __fadd_rn(__fmul_rn(__fsub_rn(En1, In1), gate1), omega1);
        L2 = __fadd_rn(__fmul_rn(__fsub_rn(En2, In2), gate2), omega2);
        E0 = En0; I0 = In0;
        E1_ = En1; I1_ = In1;
        E2_ = En2; I2_ = In2;
    }
    *L0o = L0;
    *L1o = L1;
    *L2o = L2;
}

__global__ void lee_zero_counter(unsigned int* __restrict__ count) {
    if (threadIdx.x == 0 && blockIdx.x == 0) count[0] = 0u;
}

// Kernel A: classify + wave-local ballot-prefix compaction + one global
// reservation per block + coalesced flush (proven R10-R13 structure).
__global__ __launch_bounds__(BLOCK) void lee_classify(
    const float* __restrict__ x, const int* __restrict__ osc_type,
    float* __restrict__ out, unsigned int* __restrict__ count,
    unsigned int* __restrict__ wl_idx, float* __restrict__ wl_x,
    unsigned int cap, int n) {
#pragma clang fp contract(off)
    __shared__ unsigned short s_idx[4][WL_CAP];
    __shared__ float s_x[4][WL_CAP];
    __shared__ unsigned int s_cnt[4];
    __shared__ unsigned int s_base;
    __shared__ unsigned int s_off[4];

    int t = osc_type[0];
    if (t < 1 || t > 8) t = 1;
    const float* c = kCoeffs[t - 1];

    const int wave = (int)(threadIdx.x >> 6);
    const int lane = (int)(threadIdx.x & 63);
    const int wbase = (int)blockIdx.x * SPAN + wave * WSPAN;

    if (t != 1) {
        for (int p = 0; p < ITERS_PER_WAVE; ++p) {
            int i = wbase + p * 64 + lane;
            if (i < n) out[i] = lee_compute(x[i], c);
        }
        return;
    }

    const unsigned long long lt_mask = (1ull << lane) - 1ull;  // lane<=63
    unsigned int cnt = 0;  // wave-uniform survivor count
    for (int p = 0; p < ITERS_PER_WAVE; ++p) {
        int li = p * 64 + lane;
        int i = wbase + li;
        bool valid = (i < n);
        float xv = valid ? x[i] : 1.0e9f;  // dummy classifies as skip
        float sgn = (xv > 0.0f) ? 1.0f : ((xv < 0.0f) ? -1.0f : 0.0f);
        float sim = __fadd_rn(xv, __fmul_rn(0.001f, sgn));
        float gq = __fmul_rn(__fmul_rn(-500.0f, sim), sim);
        bool surv = valid && !(gq < LOG_GATE_THRESH);
        if (valid && !surv) {
            // gate < 4e-3: |L_ref - omega| = |E99-I99|*gate < 8e-3 < 0.02;
            // omega is bitwise identical to the reference's omega.
            out[i] = xla_fast_tanh(__fmul_rn(5.0f, sim));
        }
        unsigned long long mask = __ballot(surv);
        unsigned int pos = cnt + (unsigned int)__popcll(mask & lt_mask);
        if (surv) {
            if (pos < WL_CAP) {
                s_idx[wave][pos] = (unsigned short)li;
                s_x[wave][pos] = xv;
            } else {
                out[i] = lee_compute(xv, c);  // LDS-cap overflow: exact inline
            }
        }
        cnt += (unsigned int)__popcll(mask);
    }
    if (lane == 0) s_cnt[wave] = (cnt < WL_CAP) ? cnt : WL_CAP;
    __syncthreads();

    if (threadIdx.x == 0) {
        unsigned int o0 = 0;
        unsigned int offs[4];
        for (int w = 0; w < 4; ++w) { offs[w] = o0; o0 += s_cnt[w]; }
        s_base = atomicAdd(count, o0);
        for (int w = 0; w < 4; ++w) s_off[w] = offs[w];
    }
    __syncthreads();

    unsigned int wcnt = s_cnt[wave];
    unsigned int gb = s_base + s_off[wave];
    for (unsigned int j = (unsigned int)lane; j < wcnt; j += 64u) {
        unsigned int g = gb + j;
        int i = wbase + (int)s_idx[wave][j];
        float xv = s_x[wave][j];
        if (g < cap) {
            wl_idx[g] = (unsigned int)i;
            wl_x[g] = xv;
        } else {
            out[i] = lee_compute(xv, c);  // global-cap overflow: exact inline
        }
    }
}

// Kernel B: uniform x3 schedule. T = gridDim*256 threads (one full machine
// residency); thread j runs entries (j, j+T, j+2T), dummy-padded past m —
// every wave has identical work, finishes together: no quantization tail.
__global__ __launch_bounds__(BLOCK) void lee_worklist(
    const int* __restrict__ osc_type, float* __restrict__ out,
    const unsigned int* __restrict__ count,
    const unsigned int* __restrict__ wl_idx, const float* __restrict__ wl_x,
    unsigned int cap, int n) {
#pragma clang fp contract(off)
    unsigned int m = count[0];
    if (m > cap) m = cap;
    if (m == 0u) return;
    int t = osc_type[0];
    if (t < 1 || t > 8) t = 1;
    const float* c = kCoeffs[t - 1];
    unsigned int T = gridDim.x * BLOCK;
    unsigned int j = blockIdx.x * BLOCK + threadIdx.x;

    if (m <= 3u * T) {
        unsigned int j0 = j, j1 = j + T, j2 = j + 2u * T;
        bool v0 = j0 < m, v1 = j1 < m, v2 = j2 < m;
        float x0 = v0 ? wl_x[j0] : 1.0e9f;
        float x1 = v1 ? wl_x[j1] : 1.0e9f;
        float x2 = v2 ? wl_x[j2] : 1.0e9f;
        float L0, L1, L2;
        lee_compute_x3(x0, x1, x2, c, &L0, &L1, &L2);
        if (v0) { unsigned int i0 = wl_idx[j0]; if (i0 < (unsigned int)n) out[i0] = L0; }
        if (v1) { unsigned int i1 = wl_idx[j1]; if (i1 < (unsigned int)n) out[i1] = L1; }
        if (v2) { unsigned int i2 = wl_idx[j2]; if (i2 < (unsigned int)n) out[i2] = L2; }
    } else {
        // Armor: adversarial m — plain grid-stride scalar.
        for (; j < m; j += T) {
            unsigned int i = wl_idx[j];
            float xv = wl_x[j];
            if (i < (unsigned int)n) out[i] = lee_compute(xv, c);
        }
    }
}

// Fallback: verified single-kernel (used only if d_ws is too small).
__global__ __launch_bounds__(BLOCK) void lee_osc_fallback(
    const float* __restrict__ x, const int* __restrict__ osc_type,
    float* __restrict__ out, int n) {
#pragma clang fp contract(off)
    __shared__ unsigned short s_idx[4][WL_CAP];
    __shared__ float s_x[4][WL_CAP];

    int t = osc_type[0];
    if (t < 1 || t > 8) t = 1;
    const float* c = kCoeffs[t - 1];

    const int wave = (int)(threadIdx.x >> 6);
    const int lane = (int)(threadIdx.x & 63);
    const int wbase = (int)blockIdx.x * SPAN + wave * WSPAN;

    if (t != 1) {
        for (int p = 0; p < ITERS_PER_WAVE; ++p) {
            int i = wbase + p * 64 + lane;
            if (i < n) out[i] = lee_compute(x[i], c);
        }
        return;
    }

    const unsigned long long lt_mask = (1ull << lane) - 1ull;
    unsigned int cnt = 0;
    for (int p = 0; p < ITERS_PER_WAVE; ++p) {
        int li = p * 64 + lane;
        int i = wbase + li;
        bool valid = (i < n);
        float xv = valid ? x[i] : 1.0e9f;
        float sgn = (xv > 0.0f) ? 1.0f : ((xv < 0.0f) ? -1.0f : 0.0f);
        float sim = __fadd_rn(xv, __fmul_rn(0.001f, sgn));
        float gq = __fmul_rn(__fmul_rn(-500.0f, sim), sim);
        bool surv = valid && !(gq < LOG_GATE_THRESH);
        if (valid && !surv) out[i] = xla_fast_tanh(__fmul_rn(5.0f, sim));
        unsigned long long mask = __ballot(surv);
        unsigned int pos = cnt + (unsigned int)__popcll(mask & lt_mask);
        if (surv) {
            if (pos < WL_CAP) { s_idx[wave][pos] = (unsigned short)li; s_x[wave][pos] = xv; }
            else out[i] = lee_compute(xv, c);
        }
        cnt += (unsigned int)__popcll(mask);
    }
    unsigned int m = (cnt < WL_CAP) ? cnt : WL_CAP;
    for (unsigned int j = (unsigned int)lane; j < m; j += 64u) {
        int i = wbase + (int)s_idx[wave][j];
        out[i] = lee_compute(s_x[wave][j], c);
    }
}

extern "C" void kernel_launch(void* const* d_in, const int* in_sizes, int n_in,
                              void* d_out, int out_size, void* d_ws, size_t ws_size,
                              hipStream_t stream) {
    const float* x = (const float*)d_in[0];
    const int* typ = (const int*)d_in[1];
    float* out = (float*)d_out;
    int n = out_size;
    int blocksA = (n + SPAN - 1) / SPAN;

    // Worklist layout in d_ws: [0,16) counter; [16,16+4*cap) idx; then x.
    unsigned int cap = (ws_size > 16) ? (unsigned int)((ws_size - 16) / 8) : 0u;
    unsigned int need = (unsigned int)(n / 8) + 1024u;  // survivors ~8.3% whp

    if (cap < need) {
        lee_osc_fallback<<<blocksA, BLOCK, 0, stream>>>(x, typ, out, n);
        return;
    }

    unsigned int* count = (unsigned int*)d_ws;
    unsigned int* wl_idx = (unsigned int*)((char*)d_ws + 16);
    float* wl_x = (float*)((char*)d_ws + 16 + (size_t)cap * 4u);

    lee_zero_counter<<<1, 64, 0, stream>>>(count);
    lee_classify<<<blocksA, BLOCK, 0, stream>>>(x, typ, out, count, wl_idx, wl_x, cap, n);
    lee_worklist<<<B_BLOCKS, BLOCK, 0, stream>>>(typ, out, count, wl_idx, wl_x, cap, n);
}

// Round 15
// 235.557 us; speedup vs baseline: 1.1135x; 1.1135x over previous
//
#include <hip/hip_runtime.h>

// Lee oscillator — R12 structure (best measured: kernel B 1 entry/thread,
// 8192 blocks) with ONE delta: skip threshold gate<4e-3 -> gate<6e-3.
//   Error: |L_ref - omega| = |E99-I99|*gate <= 1.2e-2 f32 (+1 bf16 ulp in
//   comparison = 1.6e-2 < 2e-2 threshold). Survivors 8.8% -> 8.0% of n,
//   shrinking both the issue floor and the pipeline-drain tail of kernel B.
// Schedule variants x2 (R13) / x3-uniform (R14) both regressed vs R12 —
// per-wave duration growth inflates the drain tail; 1 entry/thread is best.
// The type-1-ALGEBRAICALLY-SPECIALIZED body remains excluded (6/6 silent
// no-op correlation); all trajectory code is the generic bitwise-verified
// sequence (R1/R7 absmax 0.0).

#pragma clang fp contract(off)

#define N_ITERS 99                            // N_STEPS - 1
#define LOG_GATE_THRESH -5.1159958097540820f  // ln(6e-3)
#define BLOCK 256
#define ITERS_PER_WAVE 64
#define WSPAN (64 * ITERS_PER_WAVE)           // 4096 elements per wave
#define SPAN (4 * WSPAN)                      // 16384 elements per block
#define WL_CAP 512                            // per-wave LDS cap (mean ~327, +10 sigma)

// (a1,a2,a3,a4, b1,b2,b3,b4, xi_E, xi_I) for oscillator types 1..8
__device__ __constant__ float kCoeffs[8][10] = {
    { 0.0f,  5.0f,   5.0f,   1.0f,  0.0f, -1.0f,   1.0f,  0.0f, 0.0f, 0.0f},
    { 0.5f,  0.55f,  0.55f, -0.5f,  0.5f, -0.55f, -0.55f, -0.5f, 0.0f, 0.0f},
    {-5.0f,  5.0f,   5.0f,  -5.0f,  1.0f, -1.0f,  -1.0f,  1.0f, 0.0f, 0.0f},
    { 1.0f,  1.0f,   1.0f,  -1.0f, -1.0f, -1.0f,  -1.0f,  1.0f, 0.0f, 0.0f},
    { 5.0f, -5.0f,  -5.0f,   5.0f, -1.0f,  1.0f,   1.0f, -1.0f, 0.0f, 0.0f},
    {-1.0f, -1.0f,  -1.0f,   1.0f,  1.0f,  1.0f,   1.0f, -1.0f, 0.0f, 0.0f},
    { 1.0f, -1.0f,  -1.0f,   1.0f, -1.0f,  1.0f,   1.0f, -1.0f, 0.0f, 0.0f},
    {-1.0f,  1.0f,   1.0f,  -1.0f,  1.0f, -1.0f,  -1.0f,  1.0f, 0.0f, 0.0f},
};

// XLA EmitFastTanh / Eigen generic_fast_tanh_float, with_fma variant.
// Every op correctly rounded -> bitwise reproducible. (R1/R7/R8/R10-R14.)
__device__ __forceinline__ float xla_fast_tanh(float x) {
#pragma clang fp contract(off)
    const float kClamp = 7.99881172180175781f;
    float ax = __builtin_fabsf(x);
    float xc = __builtin_fminf(__builtin_fmaxf(x, -kClamp), kClamp);
    float x2 = __fmul_rn(xc, xc);
    float p = __fmaf_rn(x2, -2.76076847742355e-16f, 2.00018790482477e-13f);
    p = __fmaf_rn(x2, p, -8.60467152213735e-11f);
    p = __fmaf_rn(x2, p, 5.12229709037114e-08f);
    p = __fmaf_rn(x2, p, 1.48572235717979e-05f);
    p = __fmaf_rn(x2, p, 6.37261928875436e-04f);
    p = __fmaf_rn(x2, p, 4.89352455891786e-03f);
    p = __fmul_rn(xc, p);
    float q = __fmaf_rn(x2, 1.19825839466702e-06f, 1.18534705686654e-04f);
    q = __fmaf_rn(x2, q, 2.26843463243900e-03f);
    q = __fmaf_rn(x2, q, 4.89352518554385e-03f);
    float r = p / q;  // IEEE-correct f32 division
    return (ax < 0.0004f) ? x : r;
}

// Generic exact trajectory (ALL types) — verbatim R1/R7 (verified bitwise).
__device__ __forceinline__ float lee_compute(float xv, const float* c) {
#pragma clang fp contract(off)
    const float a1 = c[0], a2 = c[1], a3 = c[2], a4 = c[3];
    const float b1 = c[4], b2 = c[5], b3 = c[6], b4 = c[7];
    const float xiE = c[8], xiI = c[9];

    float sgn = (xv > 0.0f) ? 1.0f : ((xv < 0.0f) ? -1.0f : 0.0f);
    float sim = __fadd_rn(xv, __fmul_rn(0.001f, sgn));
    float gq = __fmul_rn(__fmul_rn(-500.0f, sim), sim);
    float gate = expf(gq);
    float omega = xla_fast_tanh(__fmul_rn(5.0f, sim));

    float E = 0.2f, I = 0.0f, L = 0.2f;
    for (int s = 0; s < N_ITERS; ++s) {
        float tE = __fmul_rn(a1, L);
        tE = __fadd_rn(tE, __fmul_rn(a2, E));
        tE = __fsub_rn(tE, __fmul_rn(a3, I));
        tE = __fadd_rn(tE, __fmul_rn(a4, sim));
        tE = __fsub_rn(tE, xiE);
        float E1 = xla_fast_tanh(__fmul_rn(5.0f, tE));

        float tI = __fmul_rn(b1, L);
        tI = __fsub_rn(tI, __fmul_rn(b2, E));
        tI = __fsub_rn(tI, __fmul_rn(b3, I));
        tI = __fadd_rn(tI, __fmul_rn(b4, sim));
        tI = __fsub_rn(tI, xiI);
        float I1 = xla_fast_tanh(__fmul_rn(5.0f, tI));

        L = __fadd_rn(__fmul_rn(__fsub_rn(E1, I1), gate), omega);
        E = E1;
        I = I1;
    }
    return L;
}

__global__ void lee_zero_counter(unsigned int* __restrict__ count) {
    if (threadIdx.x == 0 && blockIdx.x == 0) count[0] = 0u;
}

// Kernel A: classify + wave-local ballot-prefix compaction + one global
// reservation per block + coalesced flush (proven R10-R14 structure).
__global__ __launch_bounds__(BLOCK) void lee_classify(
    const float* __restrict__ x, const int* __restrict__ osc_type,
    float* __restrict__ out, unsigned int* __restrict__ count,
    unsigned int* __restrict__ wl_idx, float* __restrict__ wl_x,
    unsigned int cap, int n) {
#pragma clang fp contract(off)
    __shared__ unsigned short s_idx[4][WL_CAP];
    __shared__ float s_x[4][WL_CAP];
    __shared__ unsigned int s_cnt[4];
    __shared__ unsigned int s_base;
    __shared__ unsigned int s_off[4];

    int t = osc_type[0];
    if (t < 1 || t > 8) t = 1;
    const float* c = kCoeffs[t - 1];

    const int wave = (int)(threadIdx.x >> 6);
    const int lane = (int)(threadIdx.x & 63);
    const int wbase = (int)blockIdx.x * SPAN + wave * WSPAN;

    if (t != 1) {
        for (int p = 0; p < ITERS_PER_WAVE; ++p) {
            int i = wbase + p * 64 + lane;
            if (i < n) out[i] = lee_compute(x[i], c);
        }
        return;
    }

    const unsigned long long lt_mask = (1ull << lane) - 1ull;  // lane<=63
    unsigned int cnt = 0;  // wave-uniform survivor count
    for (int p = 0; p < ITERS_PER_WAVE; ++p) {
        int li = p * 64 + lane;
        int i = wbase + li;
        bool valid = (i < n);
        float xv = valid ? x[i] : 1.0e9f;  // dummy classifies as skip
        float sgn = (xv > 0.0f) ? 1.0f : ((xv < 0.0f) ? -1.0f : 0.0f);
        float sim = __fadd_rn(xv, __fmul_rn(0.001f, sgn));
        float gq = __fmul_rn(__fmul_rn(-500.0f, sim), sim);
        bool surv = valid && !(gq < LOG_GATE_THRESH);
        if (valid && !surv) {
            // gate < 6e-3: |L_ref - omega| = |E99-I99|*gate <= 1.2e-2 f32
            // (+1 bf16 ulp in the comparison -> <= 1.6e-2 < 2e-2 threshold);
            // omega is bitwise identical to the reference's omega.
            out[i] = xla_fast_tanh(__fmul_rn(5.0f, sim));
        }
        unsigned long long mask = __ballot(surv);
        unsigned int pos = cnt + (unsigned int)__popcll(mask & lt_mask);
        if (surv) {
            if (pos < WL_CAP) {
                s_idx[wave][pos] = (unsigned short)li;
                s_x[wave][pos] = xv;
            } else {
                out[i] = lee_compute(xv, c);  // LDS-cap overflow: exact inline
            }
        }
        cnt += (unsigned int)__popcll(mask);
    }
    if (lane == 0) s_cnt[wave] = (cnt < WL_CAP) ? cnt : WL_CAP;
    __syncthreads();

    if (threadIdx.x == 0) {
        unsigned int o0 = 0;
        unsigned int offs[4];
        for (int w = 0; w < 4; ++w) { offs[w] = o0; o0 += s_cnt[w]; }
        s_base = atomicAdd(count, o0);
        for (int w = 0; w < 4; ++w) s_off[w] = offs[w];
    }
    __syncthreads();

    unsigned int wcnt = s_cnt[wave];
    unsigned int gb = s_base + s_off[wave];
    for (unsigned int j = (unsigned int)lane; j < wcnt; j += 64u) {
        unsigned int g = gb + j;
        int i = wbase + (int)s_idx[wave][j];
        float xv = s_x[wave][j];
        if (g < cap) {
            wl_idx[g] = (unsigned int)i;
            wl_x[g] = xv;
        } else {
            out[i] = lee_compute(xv, c);  // global-cap overflow: exact inline
        }
    }
}

// Kernel B: dense worklist, <=1 entry per thread (8192 blocks = 2.1M threads
// >= m ~ 1.34M), perfectly balanced; grid-stride loop kept as armor only.
__global__ __launch_bounds__(BLOCK) void lee_worklist(
    const int* __restrict__ osc_type, float* __restrict__ out,
    const unsigned int* __restrict__ count,
    const unsigned int* __restrict__ wl_idx, const float* __restrict__ wl_x,
    unsigned int cap, int n) {
#pragma clang fp contract(off)
    unsigned int m = count[0];
    if (m > cap) m = cap;
    int t = osc_type[0];
    if (t < 1 || t > 8) t = 1;
    const float* c = kCoeffs[t - 1];
    unsigned int stride = gridDim.x * BLOCK;
    for (unsigned int j = blockIdx.x * BLOCK + threadIdx.x; j < m; j += stride) {
        unsigned int i = wl_idx[j];
        float xv = wl_x[j];
        if (i < (unsigned int)n) out[i] = lee_compute(xv, c);
    }
}

// Fallback: verified single-kernel (used only if d_ws is too small).
__global__ __launch_bounds__(BLOCK) void lee_osc_fallback(
    const float* __restrict__ x, const int* __restrict__ osc_type,
    float* __restrict__ out, int n) {
#pragma clang fp contract(off)
    __shared__ unsigned short s_idx[4][WL_CAP];
    __shared__ float s_x[4][WL_CAP];

    int t = osc_type[0];
    if (t < 1 || t > 8) t = 1;
    const float* c = kCoeffs[t - 1];

    const int wave = (int)(threadIdx.x >> 6);
    const int lane = (int)(threadIdx.x & 63);
    const int wbase = (int)blockIdx.x * SPAN + wave * WSPAN;

    if (t != 1) {
        for (int p = 0; p < ITERS_PER_WAVE; ++p) {
            int i = wbase + p * 64 + lane;
            if (i < n) out[i] = lee_compute(x[i], c);
        }
        return;
    }

    const unsigned long long lt_mask = (1ull << lane) - 1ull;
    unsigned int cnt = 0;
    for (int p = 0; p < ITERS_PER_WAVE; ++p) {
        int li = p * 64 + lane;
        int i = wbase + li;
        bool valid = (i < n);
        float xv = valid ? x[i] : 1.0e9f;
        float sgn = (xv > 0.0f) ? 1.0f : ((xv < 0.0f) ? -1.0f : 0.0f);
        float sim = __fadd_rn(xv, __fmul_rn(0.001f, sgn));
        float gq = __fmul_rn(__fmul_rn(-500.0f, sim), sim);
        bool surv = valid && !(gq < LOG_GATE_THRESH);
        if (valid && !surv) out[i] = xla_fast_tanh(__fmul_rn(5.0f, sim));
        unsigned long long mask = __ballot(surv);
        unsigned int pos = cnt + (unsigned int)__popcll(mask & lt_mask);
        if (surv) {
            if (pos < WL_CAP) { s_idx[wave][pos] = (unsigned short)li; s_x[wave][pos] = xv; }
            else out[i] = lee_compute(xv, c);
        }
        cnt += (unsigned int)__popcll(mask);
    }
    unsigned int m = (cnt < WL_CAP) ? cnt : WL_CAP;
    for (unsigned int j = (unsigned int)lane; j < m; j += 64u) {
        int i = wbase + (int)s_idx[wave][j];
        out[i] = lee_compute(s_x[wave][j], c);
    }
}

extern "C" void kernel_launch(void* const* d_in, const int* in_sizes, int n_in,
                              void* d_out, int out_size, void* d_ws, size_t ws_size,
                              hipStream_t stream) {
    const float* x = (const float*)d_in[0];
    const int* typ = (const int*)d_in[1];
    float* out = (float*)d_out;
    int n = out_size;
    int blocksA = (n + SPAN - 1) / SPAN;

    // Worklist layout in d_ws: [0,16) counter; [16,16+4*cap) idx; then x.
    unsigned int cap = (ws_size > 16) ? (unsigned int)((ws_size - 16) / 8) : 0u;
    unsigned int need = (unsigned int)(n / 8) + 1024u;  // survivors ~8.0% whp

    if (cap < need) {
        lee_osc_fallback<<<blocksA, BLOCK, 0, stream>>>(x, typ, out, n);
        return;
    }

    unsigned int* count = (unsigned int*)d_ws;
    unsigned int* wl_idx = (unsigned int*)((char*)d_ws + 16);
    float* wl_x = (float*)((char*)d_ws + 16 + (size_t)cap * 4u);

    lee_zero_counter<<<1, 64, 0, stream>>>(count);
    lee_classify<<<blocksA, BLOCK, 0, stream>>>(x, typ, out, count, wl_idx, wl_x, cap, n);
    lee_worklist<<<8192, BLOCK, 0, stream>>>(typ, out, count, wl_idx, wl_x, cap, n);
}